// Round 3
// baseline (121.507 us; speedup 1.0000x reference)
//
#include <hip/hip_runtime.h>

#define NBATCH 16
#define NANCH  3
#define NGRID  64
#define NT     60
#define NPB    (NANCH*NGRID*NGRID)   // 12288 cells per batch
#define NCELL  (NBATCH*NPB)          // 196608 total cells
#define NLBL   (NBATCH*NT)           // 960 labels
#define FEPS   1e-16f

// double accumulator slots
enum { A_XY=0, A_WH, A_IG, A_PG, A_GG, A_HM, A_GOU2, A_IOU2, A_CONFB, A_GTGOU, A_GTIOU, A_NACC };

__device__ __forceinline__ float sigm(float x) { return 1.0f / (1.0f + expf(-x)); }

__device__ __forceinline__ float waveSum(float v) {
#pragma unroll
    for (int o = 32; o > 0; o >>= 1) v += __shfl_down(v, o, 64);
    return v;
}

// ---------------------------------------------------------------------------
// Kernel A: build_target label-wise. One block, 1024 threads, j<960 active.
// ---------------------------------------------------------------------------
__global__ __launch_bounds__(1024)
void kA_build_target(const float* __restrict__ labels, const float* __restrict__ out,
                     unsigned int* __restrict__ obj_bits, double* __restrict__ acc) {
    __shared__ int keys[NLBL];
    __shared__ float red[16];
    int j = threadIdx.x;

    int b = 0, gi = 0, gj = 0, key = 0;
    float bx = 0.f, by = 0.f, lw_ = 0.f, lh_ = 0.f;
    if (j < NLBL) {
        const float* lp = labels + j * 5;
        b = (int)lp[0];
        bx = lp[1] * (float)NGRID;
        by = lp[2] * (float)NGRID;
        lw_ = lp[3];
        lh_ = lp[4];
        gi = (int)bx;
        gj = (int)by;
        key = (b * NGRID + gj) * NGRID + gi;
        keys[j] = key;
    }
    __syncthreads();

    float sxy = 0.f, swh = 0.f, sig_ = 0.f, scnt = 0.f;
    if (j < NLBL) {
        int occ = 0;
        for (int i = 0; i < j; ++i)
            if (keys[i] == key) occ++;
        if (occ < NANCH) {
            int a = occ;
            int cell = ((b * NANCH + a) * NGRID + gj) * NGRID + gi;
            atomicOr(&obj_bits[cell >> 5], 1u << (cell & 31));
            int base = ((b * NANCH * 5 + a * 5) * NGRID + gj) * NGRID + gi;
            float xs = sigm(out[base]);
            float ys = sigm(out[base + NGRID * NGRID]);
            float ws = sigm(out[base + 2 * NGRID * NGRID]);
            float hs = sigm(out[base + 3 * NGRID * NGRID]);
            float cf = sigm(out[base + 4 * NGRID * NGRID]);
            float tx = bx - floorf(bx);
            float ty = by - floorf(by);
            float dx = xs - tx, dy = ys - ty;
            sxy = dx * dx + dy * dy;
            float dw = logf(ws) - logf(lw_);
            float dh = logf(hs) - logf(lh_);
            swh = dw * dw + dh * dh;
            sig_ = cf;
            scnt = 1.f;
        }
    }

    float vals[4] = { sxy, swh, sig_, scnt };
    int wave = threadIdx.x >> 6, lane = threadIdx.x & 63;
#pragma unroll
    for (int k = 0; k < 4; ++k) {
        float v = waveSum(vals[k]);
        if (lane == 0) red[wave] = v;
        __syncthreads();
        if (threadIdx.x == 0) {
            float r = 0.f;
            for (int w = 0; w < 16; ++w) r += red[w];
            vals[k] = r;
        }
        __syncthreads();
    }
    if (threadIdx.x == 0) {
        acc[A_XY] = (double)vals[0];
        acc[A_WH] = (double)vals[1];
        acc[A_IG] = (double)vals[2];
        acc[A_GG] = (double)vals[3];
    }
}

// ---------------------------------------------------------------------------
// Kernel B: per-cell decode (stores boxes for kC3), pd-side max over 60 GTs,
// pg = sum conf^2, and fused heatmap MSE (1 float4-pair per thread).
// No cross-lane work in the t-loop.
// ---------------------------------------------------------------------------
__global__ __launch_bounds__(256)
void kB_main(const float* __restrict__ out, const float* __restrict__ labels,
             const float4* __restrict__ io4, const float4* __restrict__ hm4,
             float4* __restrict__ Pxy, float2* __restrict__ Pac,
             float* __restrict__ pd_gou, float* __restrict__ pd_iou,
             double* __restrict__ acc) {
    int idx = blockIdx.x * 256 + threadIdx.x;     // 0..NCELL-1
    int b = blockIdx.x / (NPB / 256);             // 48 blocks per batch
    int n = idx - b * NPB;

    __shared__ float G[NT][5];                    // gx1,gy1,gx2,gy2,area
    __shared__ float red[4], red2[4];
    if (threadIdx.x < NT) {
        const float* lp = labels + (b * NT + threadIdx.x) * 5;
        float gx = lp[1], gy = lp[2], gw = lp[3], gh = lp[4];
        G[threadIdx.x][0] = gx - gw * 0.5f;
        G[threadIdx.x][1] = gy - gh * 0.5f;
        G[threadIdx.x][2] = gx + gw * 0.5f;
        G[threadIdx.x][3] = gy + gh * 0.5f;
        G[threadIdx.x][4] = gw * gh;
    }
    __syncthreads();

    int a = n >> 12, gj = (n >> 6) & 63, gi = n & 63;
    int base = ((b * NANCH * 5 + a * 5) * NGRID + gj) * NGRID + gi;
    float xs = sigm(out[base]);
    float ys = sigm(out[base + NGRID * NGRID]);
    float ws = sigm(out[base + 2 * NGRID * NGRID]);
    float hs = sigm(out[base + 3 * NGRID * NGRID]);
    float cf = sigm(out[base + 4 * NGRID * NGRID]);

    float bx = (xs + (float)gi) * (1.0f / NGRID);
    float by = (ys + (float)gj) * (1.0f / NGRID);
    float px1 = bx - ws * 0.5f, px2 = bx + ws * 0.5f;
    float py1 = by - hs * 0.5f, py2 = by + hs * 0.5f;
    float pa = ws * hs;

    Pxy[idx] = make_float4(px1, py1, px2, py2);
    Pac[idx] = make_float2(pa, cf);

    float best = -1e30f, biou = 0.0f;
    for (int t = 0; t < NT; ++t) {
        float gx1 = G[t][0], gy1 = G[t][1], gx2 = G[t][2], gy2 = G[t][3], ga = G[t][4];
        float iw = fminf(px2, gx2) - fmaxf(px1, gx1); iw = fmaxf(iw, 0.f);
        float ih = fminf(py2, gy2) - fmaxf(py1, gy1); ih = fmaxf(ih, 0.f);
        float inter = iw * ih;
        float un = pa + ga - inter;
        float iou = inter / (un + FEPS);
        float cw = fmaxf(px2, gx2) - fminf(px1, gx1);
        float ch = fmaxf(py2, gy2) - fminf(py1, gy1);
        float ca = cw * ch;
        float gou = iou - (ca - un) / (ca + FEPS);
        if (gou > best) { best = gou; biou = iou; }   // first t on ties
    }
    pd_gou[idx] = best;
    pd_iou[idx] = biou;

    // fused heatmap MSE: this thread's float4 pair
    float4 ha = io4[idx], hb = hm4[idx];
    float d0 = ha.x - hb.x, d1 = ha.y - hb.y, d2 = ha.z - hb.z, d3 = ha.w - hb.w;
    float hsum = d0 * d0 + d1 * d1 + d2 * d2 + d3 * d3;

    int wave = threadIdx.x >> 6, lane = threadIdx.x & 63;
    float v = waveSum(cf * cf);
    float h = waveSum(hsum);
    if (lane == 0) { red[wave] = v; red2[wave] = h; }
    __syncthreads();
    if (threadIdx.x == 0) {
        atomicAdd(&acc[A_PG], (double)(red[0] + red[1] + red[2] + red[3]));
        atomicAdd(&acc[A_HM], (double)(red2[0] + red2[1] + red2[2] + red2[3]));
    }
}

// ---------------------------------------------------------------------------
// Kernel C3: gt-side. One block per (b,t). Reads pre-decoded boxes (L2-hot),
// (max gou, first idx) + iou-at-argmax block reduce. No decode, no per-t
// shuffle storm.
// ---------------------------------------------------------------------------
__global__ __launch_bounds__(256)
void kC3_gt(const float4* __restrict__ Pxy, const float2* __restrict__ Pac,
            const float* __restrict__ labels,
            unsigned int* __restrict__ mask_bits, double* __restrict__ acc) {
    int bt = blockIdx.x;
    int b = bt / NT;
    const float* lp = labels + bt * 5;
    float gx = lp[1], gy = lp[2], gw = lp[3], gh = lp[4];
    float gx1 = gx - gw * 0.5f, gy1 = gy - gh * 0.5f;
    float gx2 = gx + gw * 0.5f, gy2 = gy + gh * 0.5f;
    float ga = gw * gh;

    float best = -1e30f, biou = 0.0f;
    int bidx = 0x7fffffff;
    for (int n = threadIdx.x; n < NPB; n += 256) {
        int idx = b * NPB + n;
        float4 p = Pxy[idx];
        float pa = Pac[idx].x;
        float iw = fminf(p.z, gx2) - fmaxf(p.x, gx1); iw = fmaxf(iw, 0.f);
        float ih = fminf(p.w, gy2) - fmaxf(p.y, gy1); ih = fmaxf(ih, 0.f);
        float inter = iw * ih;
        float un = pa + ga - inter;
        float iou = inter / (un + FEPS);
        float cw = fmaxf(p.z, gx2) - fminf(p.x, gx1);
        float ch = fmaxf(p.w, gy2) - fminf(p.y, gy1);
        float ca = cw * ch;
        float gou = iou - (ca - un) / (ca + FEPS);
        if (gou > best) { best = gou; biou = iou; bidx = n; }  // strict >: lowest n in-thread
    }

#pragma unroll
    for (int o = 32; o > 0; o >>= 1) {
        float ov = __shfl_down(best, o, 64);
        float oiou = __shfl_down(biou, o, 64);
        int oi = __shfl_down(bidx, o, 64);
        if (ov > best || (ov == best && oi < bidx)) { best = ov; biou = oiou; bidx = oi; }
    }
    __shared__ float sv[4], siou[4];
    __shared__ int sidx[4];
    int wave = threadIdx.x >> 6, lane = threadIdx.x & 63;
    if (lane == 0) { sv[wave] = best; siou[wave] = biou; sidx[wave] = bidx; }
    __syncthreads();
    if (threadIdx.x == 0) {
        for (int w = 1; w < 4; ++w)
            if (sv[w] > best || (sv[w] == best && sidx[w] < bidx)) {
                best = sv[w]; biou = siou[w]; bidx = sidx[w];
            }
        int cell = b * NPB + bidx;
        atomicOr(&mask_bits[cell >> 5], 1u << (cell & 31));
        atomicAdd(&acc[A_GTGOU], (double)(1.0f - best));
        atomicAdd(&acc[A_GTIOU], (double)(1.0f - biou));
    }
}

// ---------------------------------------------------------------------------
// Kernel D: per-batch mask2/ignore/dice sums. 16 blocks.
// ---------------------------------------------------------------------------
__global__ __launch_bounds__(256)
void kD_batch(const float* __restrict__ pd_gou, const float* __restrict__ pd_iou,
              const float2* __restrict__ Pac, const unsigned int* __restrict__ obj_bits,
              const unsigned int* __restrict__ mask_bits, double* __restrict__ acc) {
    int b = blockIdx.x;
    float c2 = 0.f, sg = 0.f, si = 0.f, sin_ = 0.f, spa = 0.f, sga = 0.f;
    for (int n = threadIdx.x; n < NPB; n += 256) {
        int idx = b * NPB + n;
        float pio = pd_iou[idx];
        float pgo = pd_gou[idx];
        float cf = Pac[idx].y;
        bool mk = (pio >= 0.5f);
        bool m_ = (mask_bits[idx >> 5] >> (idx & 31)) & 1u;
        bool ob = (obj_bits[idx >> 5] >> (idx & 31)) & 1u;
        float m2 = (mk || m_) ? 1.f : 0.f;
        float ign = (!mk || m_) ? 1.f : 0.f;
        float tc = (ob || m_) ? 1.f : 0.f;
        c2 += m2;
        sg += (1.f - pgo) * m2;
        si += (1.f - pio) * m2;
        sin_ += cf * tc * ign;
        spa += cf * cf * ign;
        sga += tc * ign;
    }
    float vals[6] = { c2, sg, si, sin_, spa, sga };
    __shared__ float red[4];
    int wave = threadIdx.x >> 6, lane = threadIdx.x & 63;
#pragma unroll
    for (int k = 0; k < 6; ++k) {
        float v = waveSum(vals[k]);
        if (lane == 0) red[wave] = v;
        __syncthreads();
        if (threadIdx.x == 0) vals[k] = red[0] + red[1] + red[2] + red[3];
        __syncthreads();
    }
    if (threadIdx.x == 0) {
        atomicAdd(&acc[A_GOU2], (double)(vals[1] / vals[0]));
        atomicAdd(&acc[A_IOU2], (double)(vals[2] / vals[0]));
        float confb = 1.0f - (2.0f * vals[3] + 1.0f) / (vals[4] + vals[5] + 1.0f);
        atomicAdd(&acc[A_CONFB], (double)confb);
    }
}

// ---------------------------------------------------------------------------
// Kernel F: finalize the 7 outputs.
// ---------------------------------------------------------------------------
__global__ void kF_final(const double* __restrict__ acc, float* __restrict__ outp) {
    if (threadIdx.x == 0 && blockIdx.x == 0) {
        double cnt = acc[A_GG];
        double lxy = acc[A_XY] / cnt;
        double lwh = acc[A_WH] / cnt;
        double lgou = acc[A_GTGOU] / (double)NLBL + acc[A_GOU2] / (double)NBATCH;
        double liou = acc[A_GTIOU] / (double)NLBL + acc[A_IOU2] / (double)NBATCH;
        double dice = (2.0 * acc[A_IG] + 1.0) / (acc[A_PG] + acc[A_GG] + 1.0);
        if (dice != dice) dice = 1.0;
        double lconf = 1.0 - dice + acc[A_CONFB] / (double)NBATCH;
        double total = lxy + lwh + lconf + lgou;
        double hmv = acc[A_HM] / (double)(4 * NCELL);
        outp[0] = (float)lxy;
        outp[1] = (float)lwh;
        outp[2] = (float)lconf;
        outp[3] = (float)liou;
        outp[4] = (float)lgou;
        outp[5] = (float)total;
        outp[6] = (float)hmv;
    }
}

// ---------------------------------------------------------------------------
extern "C" void kernel_launch(void* const* d_in, const int* in_sizes, int n_in,
                              void* d_out, int out_size, void* d_ws, size_t ws_size,
                              hipStream_t stream) {
    const float* out_p    = (const float*)d_in[0];
    const float* labels   = (const float*)d_in[1];
    const float* int_out  = (const float*)d_in[2];
    const float* heatmaps = (const float*)d_in[3];
    float* o = (float*)d_out;

    char* ws = (char*)d_ws;
    const size_t BITS = NCELL / 8;                       // 24576 B per bitmask
    unsigned int* obj_bits  = (unsigned int*)(ws);
    unsigned int* mask_bits = (unsigned int*)(ws + BITS);
    double* acc             = (double*)(ws + 2 * BITS);  // 16 doubles
    size_t zeroed = 2 * BITS + 16 * sizeof(double);      // 49280, 16B-aligned
    float4* Pxy   = (float4*)(ws + zeroed);
    float*  pd_gou = (float*)(ws + zeroed + (size_t)NCELL * 16);
    float*  pd_iou = (float*)(ws + zeroed + (size_t)NCELL * 20);
    float2* Pac    = (float2*)(ws + zeroed + (size_t)NCELL * 24);

    hipMemsetAsync(d_ws, 0, zeroed, stream);
    hipLaunchKernelGGL(kA_build_target, dim3(1), dim3(1024), 0, stream, labels, out_p, obj_bits, acc);
    hipLaunchKernelGGL(kB_main, dim3(NCELL / 256), dim3(256), 0, stream, out_p, labels,
                       (const float4*)int_out, (const float4*)heatmaps,
                       Pxy, Pac, pd_gou, pd_iou, acc);
    hipLaunchKernelGGL(kC3_gt, dim3(NLBL), dim3(256), 0, stream, Pxy, Pac, labels, mask_bits, acc);
    hipLaunchKernelGGL(kD_batch, dim3(NBATCH), dim3(256), 0, stream, pd_gou, pd_iou, Pac,
                       obj_bits, mask_bits, acc);
    hipLaunchKernelGGL(kF_final, dim3(1), dim3(64), 0, stream, acc, o);
}

// Round 4
// 110.276 us; speedup vs baseline: 1.1018x; 1.1018x over previous
//
#include <hip/hip_runtime.h>

#define NBATCH 16
#define NANCH  3
#define NGRID  64
#define NT     60
#define NPB    (NANCH*NGRID*NGRID)   // 12288 cells per batch
#define NCELL  (NBATCH*NPB)          // 196608 total cells
#define NLBL   (NBATCH*NT)           // 960 labels
#define NSLICE 48                    // kC4: cell slices per batch (256 cells each)
#define FEPS   1e-16f

// double accumulator slots
enum { A_XY=0, A_WH, A_IG, A_PG, A_GG, A_HM, A_GOU2, A_IOU2, A_CONFB, A_GTGOU, A_GTIOU, A_NACC };

__device__ __forceinline__ float sigm(float x) { return 1.0f / (1.0f + expf(-x)); }

__device__ __forceinline__ float waveSum(float v) {
#pragma unroll
    for (int o = 32; o > 0; o >>= 1) v += __shfl_down(v, o, 64);
    return v;
}

// monotone bijection float -> u32 (order-preserving); inverse below
__device__ __forceinline__ unsigned int ford(float f) {
    unsigned int u = __float_as_uint(f);
    return (u & 0x80000000u) ? ~u : (u | 0x80000000u);
}
__device__ __forceinline__ float ford_inv(unsigned int u) {
    unsigned int v = (u & 0x80000000u) ? (u & 0x7fffffffu) : ~u;
    return __uint_as_float(v);
}

__device__ __forceinline__ void gou_pair(float px1, float py1, float px2, float py2, float pa,
                                         float gx1, float gy1, float gx2, float gy2, float ga,
                                         float& iou, float& gou) {
    float iw = fmaxf(fminf(px2, gx2) - fmaxf(px1, gx1), 0.f);
    float ih = fmaxf(fminf(py2, gy2) - fmaxf(py1, gy1), 0.f);
    float inter = iw * ih;
    float un = pa + ga - inter;
    iou = inter / (un + FEPS);
    float cw = fmaxf(px2, gx2) - fminf(px1, gx1);
    float ch = fmaxf(py2, gy2) - fminf(py1, gy1);
    float ca = cw * ch;
    gou = iou - (ca - un) / (ca + FEPS);
}

// ---------------------------------------------------------------------------
// Kernel A: build_target label-wise. One block, 1024 threads, j<960 active.
// ---------------------------------------------------------------------------
__global__ __launch_bounds__(1024)
void kA_build_target(const float* __restrict__ labels, const float* __restrict__ out,
                     unsigned int* __restrict__ obj_bits, double* __restrict__ acc) {
    __shared__ int keys[NLBL];
    __shared__ float red[16];
    int j = threadIdx.x;

    int b = 0, gi = 0, gj = 0, key = 0;
    float bx = 0.f, by = 0.f, lw_ = 0.f, lh_ = 0.f;
    if (j < NLBL) {
        const float* lp = labels + j * 5;
        b = (int)lp[0];
        bx = lp[1] * (float)NGRID;
        by = lp[2] * (float)NGRID;
        lw_ = lp[3];
        lh_ = lp[4];
        gi = (int)bx;
        gj = (int)by;
        key = (b * NGRID + gj) * NGRID + gi;
        keys[j] = key;
    }
    __syncthreads();

    float sxy = 0.f, swh = 0.f, sig_ = 0.f, scnt = 0.f;
    if (j < NLBL) {
        int occ = 0;
        for (int i = 0; i < j; ++i)
            if (keys[i] == key) occ++;
        if (occ < NANCH) {
            int a = occ;
            int cell = ((b * NANCH + a) * NGRID + gj) * NGRID + gi;
            atomicOr(&obj_bits[cell >> 5], 1u << (cell & 31));
            int base = ((b * NANCH * 5 + a * 5) * NGRID + gj) * NGRID + gi;
            float xs = sigm(out[base]);
            float ys = sigm(out[base + NGRID * NGRID]);
            float ws = sigm(out[base + 2 * NGRID * NGRID]);
            float hs = sigm(out[base + 3 * NGRID * NGRID]);
            float cf = sigm(out[base + 4 * NGRID * NGRID]);
            float tx = bx - floorf(bx);
            float ty = by - floorf(by);
            float dx = xs - tx, dy = ys - ty;
            sxy = dx * dx + dy * dy;
            float dw = logf(ws) - logf(lw_);
            float dh = logf(hs) - logf(lh_);
            swh = dw * dw + dh * dh;
            sig_ = cf;
            scnt = 1.f;
        }
    }

    float vals[4] = { sxy, swh, sig_, scnt };
    int wave = threadIdx.x >> 6, lane = threadIdx.x & 63;
#pragma unroll
    for (int k = 0; k < 4; ++k) {
        float v = waveSum(vals[k]);
        if (lane == 0) red[wave] = v;
        __syncthreads();
        if (threadIdx.x == 0) {
            float r = 0.f;
            for (int w = 0; w < 16; ++w) r += red[w];
            vals[k] = r;
        }
        __syncthreads();
    }
    if (threadIdx.x == 0) {
        acc[A_XY] = (double)vals[0];
        acc[A_WH] = (double)vals[1];
        acc[A_IG] = (double)vals[2];
        acc[A_GG] = (double)vals[3];
    }
}

// ---------------------------------------------------------------------------
// Kernel B: per-cell decode (stores boxes), pd-side max over 60 GTs,
// pg = sum conf^2, fused heatmap MSE. Unchanged from round 3.
// ---------------------------------------------------------------------------
__global__ __launch_bounds__(256)
void kB_main(const float* __restrict__ out, const float* __restrict__ labels,
             const float4* __restrict__ io4, const float4* __restrict__ hm4,
             float4* __restrict__ Pxy, float2* __restrict__ Pac,
             float* __restrict__ pd_gou, float* __restrict__ pd_iou,
             double* __restrict__ acc) {
    int idx = blockIdx.x * 256 + threadIdx.x;     // 0..NCELL-1
    int b = blockIdx.x / (NPB / 256);             // 48 blocks per batch
    int n = idx - b * NPB;

    __shared__ float G[NT][5];                    // gx1,gy1,gx2,gy2,area
    __shared__ float red[4], red2[4];
    if (threadIdx.x < NT) {
        const float* lp = labels + (b * NT + threadIdx.x) * 5;
        float gx = lp[1], gy = lp[2], gw = lp[3], gh = lp[4];
        G[threadIdx.x][0] = gx - gw * 0.5f;
        G[threadIdx.x][1] = gy - gh * 0.5f;
        G[threadIdx.x][2] = gx + gw * 0.5f;
        G[threadIdx.x][3] = gy + gh * 0.5f;
        G[threadIdx.x][4] = gw * gh;
    }
    __syncthreads();

    int a = n >> 12, gj = (n >> 6) & 63, gi = n & 63;
    int base = ((b * NANCH * 5 + a * 5) * NGRID + gj) * NGRID + gi;
    float xs = sigm(out[base]);
    float ys = sigm(out[base + NGRID * NGRID]);
    float ws = sigm(out[base + 2 * NGRID * NGRID]);
    float hs = sigm(out[base + 3 * NGRID * NGRID]);
    float cf = sigm(out[base + 4 * NGRID * NGRID]);

    float bx = (xs + (float)gi) * (1.0f / NGRID);
    float by = (ys + (float)gj) * (1.0f / NGRID);
    float px1 = bx - ws * 0.5f, px2 = bx + ws * 0.5f;
    float py1 = by - hs * 0.5f, py2 = by + hs * 0.5f;
    float pa = ws * hs;

    Pxy[idx] = make_float4(px1, py1, px2, py2);
    Pac[idx] = make_float2(pa, cf);

    float best = -1e30f, biou = 0.0f;
    for (int t = 0; t < NT; ++t) {
        float iou, gou;
        gou_pair(px1, py1, px2, py2, pa,
                 G[t][0], G[t][1], G[t][2], G[t][3], G[t][4], iou, gou);
        if (gou > best) { best = gou; biou = iou; }   // first t on ties
    }
    pd_gou[idx] = best;
    pd_iou[idx] = biou;

    // fused heatmap MSE: this thread's float4 pair
    float4 ha = io4[idx], hb = hm4[idx];
    float d0 = ha.x - hb.x, d1 = ha.y - hb.y, d2 = ha.z - hb.z, d3 = ha.w - hb.w;
    float hsum = d0 * d0 + d1 * d1 + d2 * d2 + d3 * d3;

    int wave = threadIdx.x >> 6, lane = threadIdx.x & 63;
    float v = waveSum(cf * cf);
    float h = waveSum(hsum);
    if (lane == 0) { red[wave] = v; red2[wave] = h; }
    __syncthreads();
    if (threadIdx.x == 0) {
        atomicAdd(&acc[A_PG], (double)(red[0] + red[1] + red[2] + red[3]));
        atomicAdd(&acc[A_HM], (double)(red2[0] + red2[1] + red2[2] + red2[3]));
    }
}

// ---------------------------------------------------------------------------
// Kernel C4: gt-side, transposed. Block = (batch, slice of 256 cells); each
// cell read ONCE. Thread owns one cell; 60 gous in register groups of 12;
// end-of-group pipelined shuffle reduce; per-wave winners -> LDS -> one
// atomicMax per (block,t).
// ---------------------------------------------------------------------------
__global__ __launch_bounds__(256)
void kC4_gt(const float4* __restrict__ Pxy, const float2* __restrict__ Pac,
            const float* __restrict__ labels,
            unsigned long long* __restrict__ gtbest) {
    int blk = blockIdx.x;                 // 0..16*NSLICE-1
    int b = blk / NSLICE;
    int s = blk - b * NSLICE;
    int n = s * 256 + threadIdx.x;        // cell within batch
    int idx = b * NPB + n;

    __shared__ float G[NT][5];
    __shared__ unsigned long long W[4][NT];
    if (threadIdx.x < NT) {
        const float* lp = labels + (b * NT + threadIdx.x) * 5;
        float gx = lp[1], gy = lp[2], gw = lp[3], gh = lp[4];
        G[threadIdx.x][0] = gx - gw * 0.5f;
        G[threadIdx.x][1] = gy - gh * 0.5f;
        G[threadIdx.x][2] = gx + gw * 0.5f;
        G[threadIdx.x][3] = gy + gh * 0.5f;
        G[threadIdx.x][4] = gw * gh;
    }
    __syncthreads();

    float4 p = Pxy[idx];
    float pa = Pac[idx].x;
    unsigned int invn = 0xFFFFFFFFu - (unsigned int)n;
    int wave = threadIdx.x >> 6, lane = threadIdx.x & 63;

#pragma unroll
    for (int g = 0; g < NT; g += 12) {    // 5 groups of 12 GTs
        unsigned long long pk[12];
#pragma unroll
        for (int u = 0; u < 12; ++u) {
            int t = g + u;
            float iou, gou;
            gou_pair(p.x, p.y, p.z, p.w, pa,
                     G[t][0], G[t][1], G[t][2], G[t][3], G[t][4], iou, gou);
            pk[u] = ((unsigned long long)ford(gou) << 32) | invn;
        }
        // 12 independent 6-step reduce chains (pipelined)
#pragma unroll
        for (int o = 32; o > 0; o >>= 1) {
#pragma unroll
            for (int u = 0; u < 12; ++u) {
                unsigned long long q = __shfl_down(pk[u], o, 64);
                if (q > pk[u]) pk[u] = q;
            }
        }
        if (lane == 0) {
#pragma unroll
            for (int u = 0; u < 12; ++u) W[wave][g + u] = pk[u];
        }
    }
    __syncthreads();
    if (threadIdx.x < NT) {
        unsigned long long m = W[0][threadIdx.x];
        if (W[1][threadIdx.x] > m) m = W[1][threadIdx.x];
        if (W[2][threadIdx.x] > m) m = W[2][threadIdx.x];
        if (W[3][threadIdx.x] > m) m = W[3][threadIdx.x];
        atomicMax(&gtbest[b * NT + threadIdx.x], m);
    }
}

// ---------------------------------------------------------------------------
// Kernel D: per-batch. Prologue: unpack 60 gt winners (mask bits in LDS,
// bit-exact iou recompute from stored boxes, gt gou/iou sums). Main loop:
// mask2/ignore/dice sums. 16 blocks.
// ---------------------------------------------------------------------------
__global__ __launch_bounds__(256)
void kD_batch(const float4* __restrict__ Pxy, const float2* __restrict__ Pac,
              const float* __restrict__ pd_gou, const float* __restrict__ pd_iou,
              const unsigned int* __restrict__ obj_bits,
              const unsigned long long* __restrict__ gtbest,
              const float* __restrict__ labels, double* __restrict__ acc) {
    int b = blockIdx.x;
    __shared__ unsigned int mbits[NPB / 32];   // 384 words
    for (int w = threadIdx.x; w < NPB / 32; w += 256) mbits[w] = 0u;
    __syncthreads();

    float sgou = 0.f, siou = 0.f;
    if (threadIdx.x < NT) {
        int t = threadIdx.x;
        unsigned long long pk = gtbest[b * NT + t];
        float gou = ford_inv((unsigned int)(pk >> 32));
        int n = (int)(0xFFFFFFFFu - (unsigned int)(pk & 0xFFFFFFFFu));
        atomicOr(&mbits[n >> 5], 1u << (n & 31));
        int idx = b * NPB + n;
        float4 pbx = Pxy[idx];
        float pa = Pac[idx].x;
        const float* lp = labels + (b * NT + t) * 5;
        float gx = lp[1], gy = lp[2], gw = lp[3], gh = lp[4];
        float iou, gdummy;
        gou_pair(pbx.x, pbx.y, pbx.z, pbx.w, pa,
                 gx - gw * 0.5f, gy - gh * 0.5f, gx + gw * 0.5f, gy + gh * 0.5f,
                 gw * gh, iou, gdummy);
        sgou = 1.f - gou;
        siou = 1.f - iou;
    }
    if ((threadIdx.x >> 6) == 0) {             // wave 0 only (lanes 60-63 hold 0)
        float a1 = waveSum(sgou);
        float a2 = waveSum(siou);
        if (threadIdx.x == 0) {
            atomicAdd(&acc[A_GTGOU], (double)a1);
            atomicAdd(&acc[A_GTIOU], (double)a2);
        }
    }
    __syncthreads();

    float c2 = 0.f, sg = 0.f, si = 0.f, sin_ = 0.f, spa = 0.f, sga = 0.f;
    for (int n = threadIdx.x; n < NPB; n += 256) {
        int idx = b * NPB + n;
        float pio = pd_iou[idx];
        float pgo = pd_gou[idx];
        float cf = Pac[idx].y;
        bool mk = (pio >= 0.5f);
        bool m_ = (mbits[n >> 5] >> (n & 31)) & 1u;
        bool ob = (obj_bits[idx >> 5] >> (idx & 31)) & 1u;
        float m2 = (mk || m_) ? 1.f : 0.f;
        float ign = (!mk || m_) ? 1.f : 0.f;
        float tc = (ob || m_) ? 1.f : 0.f;
        c2 += m2;
        sg += (1.f - pgo) * m2;
        si += (1.f - pio) * m2;
        sin_ += cf * tc * ign;
        spa += cf * cf * ign;
        sga += tc * ign;
    }
    float vals[6] = { c2, sg, si, sin_, spa, sga };
    __shared__ float red[4];
    int wave = threadIdx.x >> 6, lane = threadIdx.x & 63;
#pragma unroll
    for (int k = 0; k < 6; ++k) {
        float v = waveSum(vals[k]);
        if (lane == 0) red[wave] = v;
        __syncthreads();
        if (threadIdx.x == 0) vals[k] = red[0] + red[1] + red[2] + red[3];
        __syncthreads();
    }
    if (threadIdx.x == 0) {
        atomicAdd(&acc[A_GOU2], (double)(vals[1] / vals[0]));
        atomicAdd(&acc[A_IOU2], (double)(vals[2] / vals[0]));
        float confb = 1.0f - (2.0f * vals[3] + 1.0f) / (vals[4] + vals[5] + 1.0f);
        atomicAdd(&acc[A_CONFB], (double)confb);
    }
}

// ---------------------------------------------------------------------------
// Kernel F: finalize the 7 outputs.
// ---------------------------------------------------------------------------
__global__ void kF_final(const double* __restrict__ acc, float* __restrict__ outp) {
    if (threadIdx.x == 0 && blockIdx.x == 0) {
        double cnt = acc[A_GG];
        double lxy = acc[A_XY] / cnt;
        double lwh = acc[A_WH] / cnt;
        double lgou = acc[A_GTGOU] / (double)NLBL + acc[A_GOU2] / (double)NBATCH;
        double liou = acc[A_GTIOU] / (double)NLBL + acc[A_IOU2] / (double)NBATCH;
        double dice = (2.0 * acc[A_IG] + 1.0) / (acc[A_PG] + acc[A_GG] + 1.0);
        if (dice != dice) dice = 1.0;
        double lconf = 1.0 - dice + acc[A_CONFB] / (double)NBATCH;
        double total = lxy + lwh + lconf + lgou;
        double hmv = acc[A_HM] / (double)(4 * NCELL);
        outp[0] = (float)lxy;
        outp[1] = (float)lwh;
        outp[2] = (float)lconf;
        outp[3] = (float)liou;
        outp[4] = (float)lgou;
        outp[5] = (float)total;
        outp[6] = (float)hmv;
    }
}

// ---------------------------------------------------------------------------
extern "C" void kernel_launch(void* const* d_in, const int* in_sizes, int n_in,
                              void* d_out, int out_size, void* d_ws, size_t ws_size,
                              hipStream_t stream) {
    const float* out_p    = (const float*)d_in[0];
    const float* labels   = (const float*)d_in[1];
    const float* int_out  = (const float*)d_in[2];
    const float* heatmaps = (const float*)d_in[3];
    float* o = (float*)d_out;

    char* ws = (char*)d_ws;
    const size_t BITS = NCELL / 8;                                  // 24576 B
    unsigned int* obj_bits = (unsigned int*)(ws);
    double* acc            = (double*)(ws + BITS);                  // 16 doubles (128 B)
    unsigned long long* gtbest =
        (unsigned long long*)(ws + BITS + 16 * sizeof(double));     // 960 u64 (7680 B)
    size_t zeroed = BITS + 16 * sizeof(double) + (size_t)NLBL * 8;  // 32384, 16B-aligned
    float4* Pxy    = (float4*)(ws + zeroed);
    float*  pd_gou = (float*)(ws + zeroed + (size_t)NCELL * 16);
    float*  pd_iou = (float*)(ws + zeroed + (size_t)NCELL * 20);
    float2* Pac    = (float2*)(ws + zeroed + (size_t)NCELL * 24);

    hipMemsetAsync(d_ws, 0, zeroed, stream);
    hipLaunchKernelGGL(kA_build_target, dim3(1), dim3(1024), 0, stream, labels, out_p, obj_bits, acc);
    hipLaunchKernelGGL(kB_main, dim3(NCELL / 256), dim3(256), 0, stream, out_p, labels,
                       (const float4*)int_out, (const float4*)heatmaps,
                       Pxy, Pac, pd_gou, pd_iou, acc);
    hipLaunchKernelGGL(kC4_gt, dim3(NBATCH * NSLICE), dim3(256), 0, stream, Pxy, Pac, labels, gtbest);
    hipLaunchKernelGGL(kD_batch, dim3(NBATCH), dim3(256), 0, stream, Pxy, Pac, pd_gou, pd_iou,
                       obj_bits, gtbest, labels, acc);
    hipLaunchKernelGGL(kF_final, dim3(1), dim3(64), 0, stream, acc, o);
}

// Round 5
// 106.514 us; speedup vs baseline: 1.1408x; 1.0353x over previous
//
#include <hip/hip_runtime.h>

#define NBATCH 16
#define NANCH  3
#define NGRID  64
#define NT     60
#define NPB    (NANCH*NGRID*NGRID)   // 12288 cells per batch
#define NCELL  (NBATCH*NPB)          // 196608 total cells
#define NLBL   (NBATCH*NT)           // 960 labels
#define NSLICE 96                    // kC5: slices per batch (128 cells each)
#define FEPS   1e-16f

// double accumulator slots
enum { A_XY=0, A_WH, A_IG, A_PG, A_GG, A_HM, A_GOU2, A_IOU2, A_CONFB, A_GTGOU, A_GTIOU, A_NACC };

__device__ __forceinline__ float sigm(float x) { return 1.0f / (1.0f + expf(-x)); }

__device__ __forceinline__ float waveSum(float v) {
#pragma unroll
    for (int o = 32; o > 0; o >>= 1) v += __shfl_down(v, o, 64);
    return v;
}

// monotone bijection float -> u32 (order-preserving); inverse below
__device__ __forceinline__ unsigned int ford(float f) {
    unsigned int u = __float_as_uint(f);
    return (u & 0x80000000u) ? ~u : (u | 0x80000000u);
}
__device__ __forceinline__ float ford_inv(unsigned int u) {
    unsigned int v = (u & 0x80000000u) ? (u & 0x7fffffffu) : ~u;
    return __uint_as_float(v);
}

__device__ __forceinline__ void gou_pair(float px1, float py1, float px2, float py2, float pa,
                                         float gx1, float gy1, float gx2, float gy2, float ga,
                                         float& iou, float& gou) {
    float iw = fmaxf(fminf(px2, gx2) - fmaxf(px1, gx1), 0.f);
    float ih = fmaxf(fminf(py2, gy2) - fmaxf(py1, gy1), 0.f);
    float inter = iw * ih;
    float un = pa + ga - inter;
    iou = inter / (un + FEPS);
    float cw = fmaxf(px2, gx2) - fminf(px1, gx1);
    float ch = fmaxf(py2, gy2) - fminf(py1, gy1);
    float ca = cw * ch;
    gou = iou - (ca - un) / (ca + FEPS);
}

// ---------------------------------------------------------------------------
// Kernel A: build_target label-wise. One block, 1024 threads, j<960 active.
// ---------------------------------------------------------------------------
__global__ __launch_bounds__(1024)
void kA_build_target(const float* __restrict__ labels, const float* __restrict__ out,
                     unsigned int* __restrict__ obj_bits, double* __restrict__ acc) {
    __shared__ int keys[NLBL];
    __shared__ float red[16];
    int j = threadIdx.x;

    int b = 0, gi = 0, gj = 0, key = 0;
    float bx = 0.f, by = 0.f, lw_ = 0.f, lh_ = 0.f;
    if (j < NLBL) {
        const float* lp = labels + j * 5;
        b = (int)lp[0];
        bx = lp[1] * (float)NGRID;
        by = lp[2] * (float)NGRID;
        lw_ = lp[3];
        lh_ = lp[4];
        gi = (int)bx;
        gj = (int)by;
        key = (b * NGRID + gj) * NGRID + gi;
        keys[j] = key;
    }
    __syncthreads();

    float sxy = 0.f, swh = 0.f, sig_ = 0.f, scnt = 0.f;
    if (j < NLBL) {
        int occ = 0;
        for (int i = 0; i < j; ++i)
            if (keys[i] == key) occ++;
        if (occ < NANCH) {
            int a = occ;
            int cell = ((b * NANCH + a) * NGRID + gj) * NGRID + gi;
            atomicOr(&obj_bits[cell >> 5], 1u << (cell & 31));
            int base = ((b * NANCH * 5 + a * 5) * NGRID + gj) * NGRID + gi;
            float xs = sigm(out[base]);
            float ys = sigm(out[base + NGRID * NGRID]);
            float ws = sigm(out[base + 2 * NGRID * NGRID]);
            float hs = sigm(out[base + 3 * NGRID * NGRID]);
            float cf = sigm(out[base + 4 * NGRID * NGRID]);
            float tx = bx - floorf(bx);
            float ty = by - floorf(by);
            float dx = xs - tx, dy = ys - ty;
            sxy = dx * dx + dy * dy;
            float dw = logf(ws) - logf(lw_);
            float dh = logf(hs) - logf(lh_);
            swh = dw * dw + dh * dh;
            sig_ = cf;
            scnt = 1.f;
        }
    }

    float vals[4] = { sxy, swh, sig_, scnt };
    int wave = threadIdx.x >> 6, lane = threadIdx.x & 63;
#pragma unroll
    for (int k = 0; k < 4; ++k) {
        float v = waveSum(vals[k]);
        if (lane == 0) red[wave] = v;
        __syncthreads();
        if (threadIdx.x == 0) {
            float r = 0.f;
            for (int w = 0; w < 16; ++w) r += red[w];
            vals[k] = r;
        }
        __syncthreads();
    }
    if (threadIdx.x == 0) {
        acc[A_XY] = (double)vals[0];
        acc[A_WH] = (double)vals[1];
        acc[A_IG] = (double)vals[2];
        acc[A_GG] = (double)vals[3];
    }
}

// ---------------------------------------------------------------------------
// Kernel B: per-cell decode (stores boxes), pd-side max over 60 GTs,
// pg = sum conf^2, fused heatmap MSE. GT table as float4+float LDS.
// ---------------------------------------------------------------------------
__global__ __launch_bounds__(256)
void kB_main(const float* __restrict__ out, const float* __restrict__ labels,
             const float4* __restrict__ io4, const float4* __restrict__ hm4,
             float4* __restrict__ Pxy, float2* __restrict__ Pac,
             float* __restrict__ pd_gou, float* __restrict__ pd_iou,
             double* __restrict__ acc) {
    int idx = blockIdx.x * 256 + threadIdx.x;     // 0..NCELL-1
    int b = blockIdx.x / (NPB / 256);             // 48 blocks per batch
    int n = idx - b * NPB;

    __shared__ float4 G4[NT];                     // gx1,gy1,gx2,gy2
    __shared__ float  GA[NT];                     // area
    __shared__ float red[4], red2[4];
    if (threadIdx.x < NT) {
        const float* lp = labels + (b * NT + threadIdx.x) * 5;
        float gx = lp[1], gy = lp[2], gw = lp[3], gh = lp[4];
        G4[threadIdx.x] = make_float4(gx - gw * 0.5f, gy - gh * 0.5f,
                                      gx + gw * 0.5f, gy + gh * 0.5f);
        GA[threadIdx.x] = gw * gh;
    }
    __syncthreads();

    int a = n >> 12, gj = (n >> 6) & 63, gi = n & 63;
    int base = ((b * NANCH * 5 + a * 5) * NGRID + gj) * NGRID + gi;
    float xs = sigm(out[base]);
    float ys = sigm(out[base + NGRID * NGRID]);
    float ws = sigm(out[base + 2 * NGRID * NGRID]);
    float hs = sigm(out[base + 3 * NGRID * NGRID]);
    float cf = sigm(out[base + 4 * NGRID * NGRID]);

    float bx = (xs + (float)gi) * (1.0f / NGRID);
    float by = (ys + (float)gj) * (1.0f / NGRID);
    float px1 = bx - ws * 0.5f, px2 = bx + ws * 0.5f;
    float py1 = by - hs * 0.5f, py2 = by + hs * 0.5f;
    float pa = ws * hs;

    Pxy[idx] = make_float4(px1, py1, px2, py2);
    Pac[idx] = make_float2(pa, cf);

    float best = -1e30f, biou = 0.0f;
    for (int t = 0; t < NT; ++t) {
        float4 g = G4[t];
        float iou, gou;
        gou_pair(px1, py1, px2, py2, pa, g.x, g.y, g.z, g.w, GA[t], iou, gou);
        if (gou > best) { best = gou; biou = iou; }   // first t on ties
    }
    pd_gou[idx] = best;
    pd_iou[idx] = biou;

    // fused heatmap MSE: this thread's float4 pair
    float4 ha = io4[idx], hb = hm4[idx];
    float d0 = ha.x - hb.x, d1 = ha.y - hb.y, d2 = ha.z - hb.z, d3 = ha.w - hb.w;
    float hsum = d0 * d0 + d1 * d1 + d2 * d2 + d3 * d3;

    int wave = threadIdx.x >> 6, lane = threadIdx.x & 63;
    float v = waveSum(cf * cf);
    float h = waveSum(hsum);
    if (lane == 0) { red[wave] = v; red2[wave] = h; }
    __syncthreads();
    if (threadIdx.x == 0) {
        atomicAdd(&acc[A_PG], (double)(red[0] + red[1] + red[2] + red[3]));
        atomicAdd(&acc[A_HM], (double)(red2[0] + red2[1] + red2[2] + red2[3]));
    }
}

// ---------------------------------------------------------------------------
// Kernel C5: gt-side, lane-per-GT. Each wave owns 64 cells; per cell, all
// lanes evaluate gou(cell, lane_t) from a wave-uniform (scalar) box load and
// update private per-lane running max. ZERO cross-lane ops in the loop.
// One atomicMax per active lane at the end.
// ---------------------------------------------------------------------------
__global__ __launch_bounds__(256)
void kC5_gt(const float4* __restrict__ Pxy, const float2* __restrict__ Pac,
            const float* __restrict__ labels,
            unsigned long long* __restrict__ gtbest) {
    int blk = blockIdx.x;                  // 16*NSLICE blocks
    int b = blk / NSLICE;
    int s = blk - b * NSLICE;
    int wave = threadIdx.x >> 6, lane = threadIdx.x & 63;
    int t = lane < NT ? lane : 0;

    const float* lp = labels + (b * NT + t) * 5;
    float gx = lp[1], gy = lp[2], gw = lp[3], gh = lp[4];
    float gx1 = gx - gw * 0.5f, gy1 = gy - gh * 0.5f;
    float gx2 = gx + gw * 0.5f, gy2 = gy + gh * 0.5f;
    float ga = gw * gh;

    const int CPW = (NPB / NSLICE) / 4;    // cells per wave = 32
    int n0 = s * (NPB / NSLICE) + wave * CPW;

    unsigned long long best = 0ull;        // any real packed value is >= 1<<32
#pragma unroll 4
    for (int i = 0; i < CPW; ++i) {
        int n = n0 + i;
        int uidx = __builtin_amdgcn_readfirstlane(b * NPB + n);  // force SGPR/scalar load
        float4 p = Pxy[uidx];
        float pa = Pac[uidx].x;
        float iou, gou;
        gou_pair(p.x, p.y, p.z, p.w, pa, gx1, gy1, gx2, gy2, ga, iou, gou);
        unsigned long long pk = ((unsigned long long)ford(gou) << 32)
                              | (0xFFFFFFFFu - (unsigned int)n);
        if (pk > best) best = pk;          // ascending n + strict > = first-index ties
    }
    if (lane < NT) atomicMax(&gtbest[b * NT + lane], best);
}

// ---------------------------------------------------------------------------
// Kernel D: per-batch. Prologue: unpack 60 gt winners (mask bits in LDS,
// bit-exact iou recompute from stored boxes, gt gou/iou sums). Main loop:
// mask2/ignore/dice sums. 16 blocks.
// ---------------------------------------------------------------------------
__global__ __launch_bounds__(256)
void kD_batch(const float4* __restrict__ Pxy, const float2* __restrict__ Pac,
              const float* __restrict__ pd_gou, const float* __restrict__ pd_iou,
              const unsigned int* __restrict__ obj_bits,
              const unsigned long long* __restrict__ gtbest,
              const float* __restrict__ labels, double* __restrict__ acc) {
    int b = blockIdx.x;
    __shared__ unsigned int mbits[NPB / 32];   // 384 words
    for (int w = threadIdx.x; w < NPB / 32; w += 256) mbits[w] = 0u;
    __syncthreads();

    float sgou = 0.f, siou = 0.f;
    if (threadIdx.x < NT) {
        int t = threadIdx.x;
        unsigned long long pk = gtbest[b * NT + t];
        float gou = ford_inv((unsigned int)(pk >> 32));
        int n = (int)(0xFFFFFFFFu - (unsigned int)(pk & 0xFFFFFFFFu));
        atomicOr(&mbits[n >> 5], 1u << (n & 31));
        int idx = b * NPB + n;
        float4 pbx = Pxy[idx];
        float pa = Pac[idx].x;
        const float* lp = labels + (b * NT + t) * 5;
        float gx = lp[1], gy = lp[2], gw = lp[3], gh = lp[4];
        float iou, gdummy;
        gou_pair(pbx.x, pbx.y, pbx.z, pbx.w, pa,
                 gx - gw * 0.5f, gy - gh * 0.5f, gx + gw * 0.5f, gy + gh * 0.5f,
                 gw * gh, iou, gdummy);
        sgou = 1.f - gou;
        siou = 1.f - iou;
    }
    if ((threadIdx.x >> 6) == 0) {             // wave 0 only (lanes 60-63 hold 0)
        float a1 = waveSum(sgou);
        float a2 = waveSum(siou);
        if (threadIdx.x == 0) {
            atomicAdd(&acc[A_GTGOU], (double)a1);
            atomicAdd(&acc[A_GTIOU], (double)a2);
        }
    }
    __syncthreads();

    float c2 = 0.f, sg = 0.f, si = 0.f, sin_ = 0.f, spa = 0.f, sga = 0.f;
    for (int n = threadIdx.x; n < NPB; n += 256) {
        int idx = b * NPB + n;
        float pio = pd_iou[idx];
        float pgo = pd_gou[idx];
        float cf = Pac[idx].y;
        bool mk = (pio >= 0.5f);
        bool m_ = (mbits[n >> 5] >> (n & 31)) & 1u;
        bool ob = (obj_bits[idx >> 5] >> (idx & 31)) & 1u;
        float m2 = (mk || m_) ? 1.f : 0.f;
        float ign = (!mk || m_) ? 1.f : 0.f;
        float tc = (ob || m_) ? 1.f : 0.f;
        c2 += m2;
        sg += (1.f - pgo) * m2;
        si += (1.f - pio) * m2;
        sin_ += cf * tc * ign;
        spa += cf * cf * ign;
        sga += tc * ign;
    }
    float vals[6] = { c2, sg, si, sin_, spa, sga };
    __shared__ float red[4];
    int wave = threadIdx.x >> 6, lane = threadIdx.x & 63;
#pragma unroll
    for (int k = 0; k < 6; ++k) {
        float v = waveSum(vals[k]);
        if (lane == 0) red[wave] = v;
        __syncthreads();
        if (threadIdx.x == 0) vals[k] = red[0] + red[1] + red[2] + red[3];
        __syncthreads();
    }
    if (threadIdx.x == 0) {
        atomicAdd(&acc[A_GOU2], (double)(vals[1] / vals[0]));
        atomicAdd(&acc[A_IOU2], (double)(vals[2] / vals[0]));
        float confb = 1.0f - (2.0f * vals[3] + 1.0f) / (vals[4] + vals[5] + 1.0f);
        atomicAdd(&acc[A_CONFB], (double)confb);
    }
}

// ---------------------------------------------------------------------------
// Kernel F: finalize the 7 outputs.
// ---------------------------------------------------------------------------
__global__ void kF_final(const double* __restrict__ acc, float* __restrict__ outp) {
    if (threadIdx.x == 0 && blockIdx.x == 0) {
        double cnt = acc[A_GG];
        double lxy = acc[A_XY] / cnt;
        double lwh = acc[A_WH] / cnt;
        double lgou = acc[A_GTGOU] / (double)NLBL + acc[A_GOU2] / (double)NBATCH;
        double liou = acc[A_GTIOU] / (double)NLBL + acc[A_IOU2] / (double)NBATCH;
        double dice = (2.0 * acc[A_IG] + 1.0) / (acc[A_PG] + acc[A_GG] + 1.0);
        if (dice != dice) dice = 1.0;
        double lconf = 1.0 - dice + acc[A_CONFB] / (double)NBATCH;
        double total = lxy + lwh + lconf + lgou;
        double hmv = acc[A_HM] / (double)(4 * NCELL);
        outp[0] = (float)lxy;
        outp[1] = (float)lwh;
        outp[2] = (float)lconf;
        outp[3] = (float)liou;
        outp[4] = (float)lgou;
        outp[5] = (float)total;
        outp[6] = (float)hmv;
    }
}

// ---------------------------------------------------------------------------
extern "C" void kernel_launch(void* const* d_in, const int* in_sizes, int n_in,
                              void* d_out, int out_size, void* d_ws, size_t ws_size,
                              hipStream_t stream) {
    const float* out_p    = (const float*)d_in[0];
    const float* labels   = (const float*)d_in[1];
    const float* int_out  = (const float*)d_in[2];
    const float* heatmaps = (const float*)d_in[3];
    float* o = (float*)d_out;

    char* ws = (char*)d_ws;
    const size_t BITS = NCELL / 8;                                  // 24576 B
    unsigned int* obj_bits = (unsigned int*)(ws);
    double* acc            = (double*)(ws + BITS);                  // 16 doubles (128 B)
    unsigned long long* gtbest =
        (unsigned long long*)(ws + BITS + 16 * sizeof(double));     // 960 u64 (7680 B)
    size_t zeroed = BITS + 16 * sizeof(double) + (size_t)NLBL * 8;  // 32384, 16B-aligned
    float4* Pxy    = (float4*)(ws + zeroed);
    float*  pd_gou = (float*)(ws + zeroed + (size_t)NCELL * 16);
    float*  pd_iou = (float*)(ws + zeroed + (size_t)NCELL * 20);
    float2* Pac    = (float2*)(ws + zeroed + (size_t)NCELL * 24);

    hipMemsetAsync(d_ws, 0, zeroed, stream);
    hipLaunchKernelGGL(kA_build_target, dim3(1), dim3(1024), 0, stream, labels, out_p, obj_bits, acc);
    hipLaunchKernelGGL(kB_main, dim3(NCELL / 256), dim3(256), 0, stream, out_p, labels,
                       (const float4*)int_out, (const float4*)heatmaps,
                       Pxy, Pac, pd_gou, pd_iou, acc);
    hipLaunchKernelGGL(kC5_gt, dim3(NBATCH * NSLICE), dim3(256), 0, stream, Pxy, Pac, labels, gtbest);
    hipLaunchKernelGGL(kD_batch, dim3(NBATCH), dim3(256), 0, stream, Pxy, Pac, pd_gou, pd_iou,
                       obj_bits, gtbest, labels, acc);
    hipLaunchKernelGGL(kF_final, dim3(1), dim3(64), 0, stream, acc, o);
}

// Round 6
// 87.731 us; speedup vs baseline: 1.3850x; 1.2141x over previous
//
#include <hip/hip_runtime.h>

#define NBATCH 16
#define NANCH  3
#define NGRID  64
#define NT     60
#define NPB    (NANCH*NGRID*NGRID)   // 12288 cells per batch
#define NCELL  (NBATCH*NPB)          // 196608 total cells
#define NLBL   (NBATCH*NT)           // 960 labels
#define NBPB   (NPB/256)             // 48 kB-blocks per batch
#define FEPS   1e-16f

// double accumulator slots
enum { A_XY=0, A_WH, A_IG, A_PG, A_GG, A_HM, A_GOU2, A_IOU2, A_CONFB, A_GTGOU, A_GTIOU, A_NACC };

__device__ __forceinline__ float sigm(float x) { return 1.0f / (1.0f + expf(-x)); }

__device__ __forceinline__ float waveSum(float v) {
#pragma unroll
    for (int o = 32; o > 0; o >>= 1) v += __shfl_down(v, o, 64);
    return v;
}

// monotone bijection float -> u32 (order-preserving); inverse below
__device__ __forceinline__ unsigned int ford(float f) {
    unsigned int u = __float_as_uint(f);
    return (u & 0x80000000u) ? ~u : (u | 0x80000000u);
}
__device__ __forceinline__ float ford_inv(unsigned int u) {
    unsigned int v = (u & 0x80000000u) ? (u & 0x7fffffffu) : ~u;
    return __uint_as_float(v);
}

__device__ __forceinline__ void gou_pair(float px1, float py1, float px2, float py2, float pa,
                                         float gx1, float gy1, float gx2, float gy2, float ga,
                                         float& iou, float& gou) {
    float iw = fmaxf(fminf(px2, gx2) - fmaxf(px1, gx1), 0.f);
    float ih = fmaxf(fminf(py2, gy2) - fmaxf(py1, gy1), 0.f);
    float inter = iw * ih;
    float un = pa + ga - inter;
    iou = inter / (un + FEPS);
    float cw = fmaxf(px2, gx2) - fminf(px1, gx1);
    float ch = fmaxf(py2, gy2) - fminf(py1, gy1);
    float ca = cw * ch;
    gou = iou - (ca - un) / (ca + FEPS);
}

// ---------------------------------------------------------------------------
// Kernel A: zero control state (replaces hipMemsetAsync — 40us fill dispatch!)
// then build_target label-wise. One block, 1024 threads, j<960 active.
// ---------------------------------------------------------------------------
__global__ __launch_bounds__(1024)
void kA_build_target(const float* __restrict__ labels, const float* __restrict__ out,
                     unsigned int* __restrict__ obj_bits,
                     unsigned long long* __restrict__ gtbest,
                     double* __restrict__ acc) {
    // --- zero phase (single block; visible to later kernels via stream order)
    for (int i = threadIdx.x; i < NCELL / 32; i += 1024) obj_bits[i] = 0u;
    for (int i = threadIdx.x; i < NLBL; i += 1024) gtbest[i] = 0ull;
    if (threadIdx.x < A_NACC) acc[threadIdx.x] = 0.0;

    __shared__ int keys[NLBL];
    __shared__ float red[16];
    int j = threadIdx.x;

    int b = 0, gi = 0, gj = 0, key = 0;
    float bx = 0.f, by = 0.f, lw_ = 0.f, lh_ = 0.f;
    if (j < NLBL) {
        const float* lp = labels + j * 5;
        b = (int)lp[0];
        bx = lp[1] * (float)NGRID;
        by = lp[2] * (float)NGRID;
        lw_ = lp[3];
        lh_ = lp[4];
        gi = (int)bx;
        gj = (int)by;
        key = (b * NGRID + gj) * NGRID + gi;
        keys[j] = key;
    }
    __syncthreads();   // zero phase + keys complete

    float sxy = 0.f, swh = 0.f, sig_ = 0.f, scnt = 0.f;
    if (j < NLBL) {
        int occ = 0;
        for (int i = 0; i < j; ++i)
            if (keys[i] == key) occ++;
        if (occ < NANCH) {
            int a = occ;
            int cell = ((b * NANCH + a) * NGRID + gj) * NGRID + gi;
            atomicOr(&obj_bits[cell >> 5], 1u << (cell & 31));
            int base = ((b * NANCH * 5 + a * 5) * NGRID + gj) * NGRID + gi;
            float xs = sigm(out[base]);
            float ys = sigm(out[base + NGRID * NGRID]);
            float ws = sigm(out[base + 2 * NGRID * NGRID]);
            float hs = sigm(out[base + 3 * NGRID * NGRID]);
            float cf = sigm(out[base + 4 * NGRID * NGRID]);
            float tx = bx - floorf(bx);
            float ty = by - floorf(by);
            float dx = xs - tx, dy = ys - ty;
            sxy = dx * dx + dy * dy;
            float dw = logf(ws) - logf(lw_);
            float dh = logf(hs) - logf(lh_);
            swh = dw * dw + dh * dh;
            sig_ = cf;
            scnt = 1.f;
        }
    }

    float vals[4] = { sxy, swh, sig_, scnt };
    int wave = threadIdx.x >> 6, lane = threadIdx.x & 63;
#pragma unroll
    for (int k = 0; k < 4; ++k) {
        float v = waveSum(vals[k]);
        if (lane == 0) red[wave] = v;
        __syncthreads();
        if (threadIdx.x == 0) {
            float r = 0.f;
            for (int w = 0; w < 16; ++w) r += red[w];
            vals[k] = r;
        }
        __syncthreads();
    }
    if (threadIdx.x == 0) {
        acc[A_XY] = (double)vals[0];
        acc[A_WH] = (double)vals[1];
        acc[A_IG] = (double)vals[2];
        acc[A_GG] = (double)vals[3];
    }
}

// ---------------------------------------------------------------------------
// Kernel B (fused): per-cell decode (stores boxes), pd-side max over 60 GTs,
// gt-side lane-per-GT pass over this block's 256 boxes via LDS broadcast
// (zero cross-lane ops, one atomicMax per lane), pg, fused heatmap MSE.
// ---------------------------------------------------------------------------
__global__ __launch_bounds__(256)
void kB_main(const float* __restrict__ out, const float* __restrict__ labels,
             const float4* __restrict__ io4, const float4* __restrict__ hm4,
             float4* __restrict__ Pxy, float2* __restrict__ Pac,
             float* __restrict__ pd_gou, float* __restrict__ pd_iou,
             unsigned long long* __restrict__ gtbest, double* __restrict__ acc) {
    int idx = blockIdx.x * 256 + threadIdx.x;     // 0..NCELL-1
    int b = blockIdx.x / NBPB;                    // 48 blocks per batch
    int s = blockIdx.x - b * NBPB;                // slice within batch
    int n = s * 256 + threadIdx.x;                // cell within batch
    int wave = threadIdx.x >> 6, lane = threadIdx.x & 63;

    __shared__ float4 G4[NT];                     // gx1,gy1,gx2,gy2
    __shared__ float  GA[NT];                     // area
    __shared__ float4 Bxy[256];                   // this block's boxes
    __shared__ float  Bpa[256];
    __shared__ float red[4], red2[4];
    if (threadIdx.x < NT) {
        const float* lp = labels + (b * NT + threadIdx.x) * 5;
        float gx = lp[1], gy = lp[2], gw = lp[3], gh = lp[4];
        G4[threadIdx.x] = make_float4(gx - gw * 0.5f, gy - gh * 0.5f,
                                      gx + gw * 0.5f, gy + gh * 0.5f);
        GA[threadIdx.x] = gw * gh;
    }

    int a = n >> 12, gj = (n >> 6) & 63, gi = n & 63;
    int base = ((b * NANCH * 5 + a * 5) * NGRID + gj) * NGRID + gi;
    float xs = sigm(out[base]);
    float ys = sigm(out[base + NGRID * NGRID]);
    float ws = sigm(out[base + 2 * NGRID * NGRID]);
    float hs = sigm(out[base + 3 * NGRID * NGRID]);
    float cf = sigm(out[base + 4 * NGRID * NGRID]);

    float bx = (xs + (float)gi) * (1.0f / NGRID);
    float by = (ys + (float)gj) * (1.0f / NGRID);
    float px1 = bx - ws * 0.5f, px2 = bx + ws * 0.5f;
    float py1 = by - hs * 0.5f, py2 = by + hs * 0.5f;
    float pa = ws * hs;

    Pxy[idx] = make_float4(px1, py1, px2, py2);
    Pac[idx] = make_float2(pa, cf);
    Bxy[threadIdx.x] = make_float4(px1, py1, px2, py2);
    Bpa[threadIdx.x] = pa;
    __syncthreads();                              // G4/GA + Bxy/Bpa ready

    // --- pd-side: this cell vs all 60 GTs (first-t tie-break)
    float best = -1e30f, biou = 0.0f;
    for (int t = 0; t < NT; ++t) {
        float4 g = G4[t];
        float iou, gou;
        gou_pair(px1, py1, px2, py2, pa, g.x, g.y, g.z, g.w, GA[t], iou, gou);
        if (gou > best) { best = gou; biou = iou; }
    }
    pd_gou[idx] = best;
    pd_iou[idx] = biou;

    // --- gt-side: lane = GT t; wave scans its 64 cells via LDS broadcast.
    {
        int t = (lane < NT) ? lane : 0;
        float4 g = G4[t];
        float ga = GA[t];
        int cbase = wave * 64;
        int nbase = s * 256 + cbase;
        unsigned long long bestp = 0ull;          // any real packed value >= 1<<32
#pragma unroll 4
        for (int i = 0; i < 64; ++i) {
            float4 p = Bxy[cbase + i];            // wave-uniform address: broadcast
            float cpa = Bpa[cbase + i];
            float iou, gou;
            gou_pair(p.x, p.y, p.z, p.w, cpa, g.x, g.y, g.z, g.w, ga, iou, gou);
            unsigned long long pk = ((unsigned long long)ford(gou) << 32)
                                  | (0xFFFFFFFFu - (unsigned int)(nbase + i));
            if (pk > bestp) bestp = pk;           // ascending n + strict > = first-index
        }
        if (lane < NT) atomicMax(&gtbest[b * NT + lane], bestp);
    }

    // --- fused heatmap MSE + pg
    float4 ha = io4[idx], hb = hm4[idx];
    float d0 = ha.x - hb.x, d1 = ha.y - hb.y, d2 = ha.z - hb.z, d3 = ha.w - hb.w;
    float hsum = d0 * d0 + d1 * d1 + d2 * d2 + d3 * d3;

    float v = waveSum(cf * cf);
    float h = waveSum(hsum);
    if (lane == 0) { red[wave] = v; red2[wave] = h; }
    __syncthreads();
    if (threadIdx.x == 0) {
        atomicAdd(&acc[A_PG], (double)(red[0] + red[1] + red[2] + red[3]));
        atomicAdd(&acc[A_HM], (double)(red2[0] + red2[1] + red2[2] + red2[3]));
    }
}

// ---------------------------------------------------------------------------
// Kernel D: per-batch. Prologue: unpack 60 gt winners (mask bits in LDS,
// bit-exact iou recompute from stored boxes, gt gou/iou sums). Main loop:
// mask2/ignore/dice sums. 16 blocks.
// ---------------------------------------------------------------------------
__global__ __launch_bounds__(256)
void kD_batch(const float4* __restrict__ Pxy, const float2* __restrict__ Pac,
              const float* __restrict__ pd_gou, const float* __restrict__ pd_iou,
              const unsigned int* __restrict__ obj_bits,
              const unsigned long long* __restrict__ gtbest,
              const float* __restrict__ labels, double* __restrict__ acc) {
    int b = blockIdx.x;
    __shared__ unsigned int mbits[NPB / 32];   // 384 words
    for (int w = threadIdx.x; w < NPB / 32; w += 256) mbits[w] = 0u;
    __syncthreads();

    float sgou = 0.f, siou = 0.f;
    if (threadIdx.x < NT) {
        int t = threadIdx.x;
        unsigned long long pk = gtbest[b * NT + t];
        float gou = ford_inv((unsigned int)(pk >> 32));
        int n = (int)(0xFFFFFFFFu - (unsigned int)(pk & 0xFFFFFFFFu));
        atomicOr(&mbits[n >> 5], 1u << (n & 31));
        int idx = b * NPB + n;
        float4 pbx = Pxy[idx];
        float pa = Pac[idx].x;
        const float* lp = labels + (b * NT + t) * 5;
        float gx = lp[1], gy = lp[2], gw = lp[3], gh = lp[4];
        float iou, gdummy;
        gou_pair(pbx.x, pbx.y, pbx.z, pbx.w, pa,
                 gx - gw * 0.5f, gy - gh * 0.5f, gx + gw * 0.5f, gy + gh * 0.5f,
                 gw * gh, iou, gdummy);
        sgou = 1.f - gou;
        siou = 1.f - iou;
    }
    if ((threadIdx.x >> 6) == 0) {             // wave 0 only (lanes 60-63 hold 0)
        float a1 = waveSum(sgou);
        float a2 = waveSum(siou);
        if (threadIdx.x == 0) {
            atomicAdd(&acc[A_GTGOU], (double)a1);
            atomicAdd(&acc[A_GTIOU], (double)a2);
        }
    }
    __syncthreads();

    float c2 = 0.f, sg = 0.f, si = 0.f, sin_ = 0.f, spa = 0.f, sga = 0.f;
    for (int n = threadIdx.x; n < NPB; n += 256) {
        int idx = b * NPB + n;
        float pio = pd_iou[idx];
        float pgo = pd_gou[idx];
        float cf = Pac[idx].y;
        bool mk = (pio >= 0.5f);
        bool m_ = (mbits[n >> 5] >> (n & 31)) & 1u;
        bool ob = (obj_bits[idx >> 5] >> (idx & 31)) & 1u;
        float m2 = (mk || m_) ? 1.f : 0.f;
        float ign = (!mk || m_) ? 1.f : 0.f;
        float tc = (ob || m_) ? 1.f : 0.f;
        c2 += m2;
        sg += (1.f - pgo) * m2;
        si += (1.f - pio) * m2;
        sin_ += cf * tc * ign;
        spa += cf * cf * ign;
        sga += tc * ign;
    }
    float vals[6] = { c2, sg, si, sin_, spa, sga };
    __shared__ float red[4];
    int wave = threadIdx.x >> 6, lane = threadIdx.x & 63;
#pragma unroll
    for (int k = 0; k < 6; ++k) {
        float v = waveSum(vals[k]);
        if (lane == 0) red[wave] = v;
        __syncthreads();
        if (threadIdx.x == 0) vals[k] = red[0] + red[1] + red[2] + red[3];
        __syncthreads();
    }
    if (threadIdx.x == 0) {
        atomicAdd(&acc[A_GOU2], (double)(vals[1] / vals[0]));
        atomicAdd(&acc[A_IOU2], (double)(vals[2] / vals[0]));
        float confb = 1.0f - (2.0f * vals[3] + 1.0f) / (vals[4] + vals[5] + 1.0f);
        atomicAdd(&acc[A_CONFB], (double)confb);
    }
}

// ---------------------------------------------------------------------------
// Kernel F: finalize the 7 outputs.
// ---------------------------------------------------------------------------
__global__ void kF_final(const double* __restrict__ acc, float* __restrict__ outp) {
    if (threadIdx.x == 0 && blockIdx.x == 0) {
        double cnt = acc[A_GG];
        double lxy = acc[A_XY] / cnt;
        double lwh = acc[A_WH] / cnt;
        double lgou = acc[A_GTGOU] / (double)NLBL + acc[A_GOU2] / (double)NBATCH;
        double liou = acc[A_GTIOU] / (double)NLBL + acc[A_IOU2] / (double)NBATCH;
        double dice = (2.0 * acc[A_IG] + 1.0) / (acc[A_PG] + acc[A_GG] + 1.0);
        if (dice != dice) dice = 1.0;
        double lconf = 1.0 - dice + acc[A_CONFB] / (double)NBATCH;
        double total = lxy + lwh + lconf + lgou;
        double hmv = acc[A_HM] / (double)(4 * NCELL);
        outp[0] = (float)lxy;
        outp[1] = (float)lwh;
        outp[2] = (float)lconf;
        outp[3] = (float)liou;
        outp[4] = (float)lgou;
        outp[5] = (float)total;
        outp[6] = (float)hmv;
    }
}

// ---------------------------------------------------------------------------
extern "C" void kernel_launch(void* const* d_in, const int* in_sizes, int n_in,
                              void* d_out, int out_size, void* d_ws, size_t ws_size,
                              hipStream_t stream) {
    const float* out_p    = (const float*)d_in[0];
    const float* labels   = (const float*)d_in[1];
    const float* int_out  = (const float*)d_in[2];
    const float* heatmaps = (const float*)d_in[3];
    float* o = (float*)d_out;

    char* ws = (char*)d_ws;
    const size_t BITS = NCELL / 8;                                  // 24576 B
    unsigned int* obj_bits = (unsigned int*)(ws);
    double* acc            = (double*)(ws + BITS);                  // 16 doubles (128 B)
    unsigned long long* gtbest =
        (unsigned long long*)(ws + BITS + 16 * sizeof(double));     // 960 u64 (7680 B)
    size_t hdr = BITS + 16 * sizeof(double) + (size_t)NLBL * 8;     // 32384, 16B-aligned
    float4* Pxy    = (float4*)(ws + hdr);
    float*  pd_gou = (float*)(ws + hdr + (size_t)NCELL * 16);
    float*  pd_iou = (float*)(ws + hdr + (size_t)NCELL * 20);
    float2* Pac    = (float2*)(ws + hdr + (size_t)NCELL * 24);

    // no memset: kA zeroes obj_bits/gtbest/acc; kB fully overwrites the rest.
    hipLaunchKernelGGL(kA_build_target, dim3(1), dim3(1024), 0, stream,
                       labels, out_p, obj_bits, gtbest, acc);
    hipLaunchKernelGGL(kB_main, dim3(NCELL / 256), dim3(256), 0, stream, out_p, labels,
                       (const float4*)int_out, (const float4*)heatmaps,
                       Pxy, Pac, pd_gou, pd_iou, gtbest, acc);
    hipLaunchKernelGGL(kD_batch, dim3(NBATCH), dim3(256), 0, stream, Pxy, Pac, pd_gou, pd_iou,
                       obj_bits, gtbest, labels, acc);
    hipLaunchKernelGGL(kF_final, dim3(1), dim3(64), 0, stream, acc, o);
}

// Round 7
// 76.368 us; speedup vs baseline: 1.5911x; 1.1488x over previous
//
#include <hip/hip_runtime.h>

#define NBATCH 16
#define NANCH  3
#define NGRID  64
#define NT     60
#define NPB    (NANCH*NGRID*NGRID)   // 12288 cells per batch
#define NCELL  (NBATCH*NPB)          // 196608 total cells
#define NLBL   (NBATCH*NT)           // 960 labels
#define NBPB   (NPB/256)             // 48 kB-blocks per batch
#define FEPS   1e-16f

// double accumulator slots
enum { A_XY=0, A_WH, A_IG, A_PG, A_GG, A_HM, A_GOU2, A_IOU2, A_CONFB, A_GTGOU, A_GTIOU, A_NACC };

// fast approx reciprocal (v_rcp_f32, ~1ulp) — used for EVERY division in the
// gou/sigmoid path so pd-side, gt-side and kD recompute stay value-identical.
__device__ __forceinline__ float frcp(float x) { return __builtin_amdgcn_rcpf(x); }

__device__ __forceinline__ float sigm(float x) { return frcp(1.0f + __expf(-x)); }

__device__ __forceinline__ float waveSum(float v) {
#pragma unroll
    for (int o = 32; o > 0; o >>= 1) v += __shfl_down(v, o, 64);
    return v;
}

// monotone bijection float -> u32 (order-preserving); inverse below
__device__ __forceinline__ unsigned int ford(float f) {
    unsigned int u = __float_as_uint(f);
    return (u & 0x80000000u) ? ~u : (u | 0x80000000u);
}
__device__ __forceinline__ float ford_inv(unsigned int u) {
    unsigned int v = (u & 0x80000000u) ? (u & 0x7fffffffu) : ~u;
    return __uint_as_float(v);
}

__device__ __forceinline__ void gou_pair(float px1, float py1, float px2, float py2, float pa,
                                         float gx1, float gy1, float gx2, float gy2, float ga,
                                         float& iou, float& gou) {
    float iw = fmaxf(fminf(px2, gx2) - fmaxf(px1, gx1), 0.f);
    float ih = fmaxf(fminf(py2, gy2) - fmaxf(py1, gy1), 0.f);
    float inter = iw * ih;
    float un = pa + ga - inter;
    iou = inter * frcp(un + FEPS);
    float cw = fmaxf(px2, gx2) - fminf(px1, gx1);
    float ch = fmaxf(py2, gy2) - fminf(py1, gy1);
    float ca = cw * ch;
    gou = iou - (ca - un) * frcp(ca + FEPS);
}

// ---------------------------------------------------------------------------
// Kernel A: zero control state (replaces hipMemsetAsync — 40us fill dispatch!)
// then build_target label-wise. One block, 1024 threads, j<960 active.
// ---------------------------------------------------------------------------
__global__ __launch_bounds__(1024)
void kA_build_target(const float* __restrict__ labels, const float* __restrict__ out,
                     unsigned int* __restrict__ obj_bits,
                     unsigned long long* __restrict__ gtbest,
                     double* __restrict__ acc) {
    // --- zero phase (single block; visible to later kernels via stream order)
    for (int i = threadIdx.x; i < NCELL / 32; i += 1024) obj_bits[i] = 0u;
    for (int i = threadIdx.x; i < NLBL; i += 1024) gtbest[i] = 0ull;
    if (threadIdx.x < A_NACC) acc[threadIdx.x] = 0.0;

    __shared__ int keys[NLBL];
    __shared__ float red[16];
    int j = threadIdx.x;

    int b = 0, gi = 0, gj = 0, key = 0;
    float bx = 0.f, by = 0.f, lw_ = 0.f, lh_ = 0.f;
    if (j < NLBL) {
        const float* lp = labels + j * 5;
        b = (int)lp[0];
        bx = lp[1] * (float)NGRID;
        by = lp[2] * (float)NGRID;
        lw_ = lp[3];
        lh_ = lp[4];
        gi = (int)bx;
        gj = (int)by;
        key = (b * NGRID + gj) * NGRID + gi;
        keys[j] = key;
    }
    __syncthreads();   // zero phase + keys complete

    float sxy = 0.f, swh = 0.f, sig_ = 0.f, scnt = 0.f;
    if (j < NLBL) {
        int occ = 0;
        for (int i = 0; i < j; ++i)
            if (keys[i] == key) occ++;
        if (occ < NANCH) {
            int a = occ;
            int cell = ((b * NANCH + a) * NGRID + gj) * NGRID + gi;
            atomicOr(&obj_bits[cell >> 5], 1u << (cell & 31));
            int base = ((b * NANCH * 5 + a * 5) * NGRID + gj) * NGRID + gi;
            float xs = sigm(out[base]);
            float ys = sigm(out[base + NGRID * NGRID]);
            float ws = sigm(out[base + 2 * NGRID * NGRID]);
            float hs = sigm(out[base + 3 * NGRID * NGRID]);
            float cf = sigm(out[base + 4 * NGRID * NGRID]);
            float tx = bx - floorf(bx);
            float ty = by - floorf(by);
            float dx = xs - tx, dy = ys - ty;
            sxy = dx * dx + dy * dy;
            float dw = __logf(ws) - __logf(lw_);
            float dh = __logf(hs) - __logf(lh_);
            swh = dw * dw + dh * dh;
            sig_ = cf;
            scnt = 1.f;
        }
    }

    float vals[4] = { sxy, swh, sig_, scnt };
    int wave = threadIdx.x >> 6, lane = threadIdx.x & 63;
#pragma unroll
    for (int k = 0; k < 4; ++k) {
        float v = waveSum(vals[k]);
        if (lane == 0) red[wave] = v;
        __syncthreads();
        if (threadIdx.x == 0) {
            float r = 0.f;
            for (int w = 0; w < 16; ++w) r += red[w];
            vals[k] = r;
        }
        __syncthreads();
    }
    if (threadIdx.x == 0) {
        acc[A_XY] = (double)vals[0];
        acc[A_WH] = (double)vals[1];
        acc[A_IG] = (double)vals[2];
        acc[A_GG] = (double)vals[3];
    }
}

// ---------------------------------------------------------------------------
// Kernel B (fused): per-cell decode (stores boxes), pd-side max over 60 GTs,
// gt-side lane-per-GT pass over this block's 256 boxes via LDS broadcast
// (zero cross-lane ops, one atomicMax per lane), pg, fused heatmap MSE.
// ---------------------------------------------------------------------------
__global__ __launch_bounds__(256)
void kB_main(const float* __restrict__ out, const float* __restrict__ labels,
             const float4* __restrict__ io4, const float4* __restrict__ hm4,
             float4* __restrict__ Pxy, float2* __restrict__ Pac,
             float* __restrict__ pd_gou, float* __restrict__ pd_iou,
             unsigned long long* __restrict__ gtbest, double* __restrict__ acc) {
    int idx = blockIdx.x * 256 + threadIdx.x;     // 0..NCELL-1
    int b = blockIdx.x / NBPB;                    // 48 blocks per batch
    int s = blockIdx.x - b * NBPB;                // slice within batch
    int n = s * 256 + threadIdx.x;                // cell within batch
    int wave = threadIdx.x >> 6, lane = threadIdx.x & 63;

    __shared__ float4 G4[NT];                     // gx1,gy1,gx2,gy2
    __shared__ float  GA[NT];                     // area
    __shared__ float4 Bxy[256];                   // this block's boxes
    __shared__ float  Bpa[256];
    __shared__ float red[4], red2[4];
    if (threadIdx.x < NT) {
        const float* lp = labels + (b * NT + threadIdx.x) * 5;
        float gx = lp[1], gy = lp[2], gw = lp[3], gh = lp[4];
        G4[threadIdx.x] = make_float4(gx - gw * 0.5f, gy - gh * 0.5f,
                                      gx + gw * 0.5f, gy + gh * 0.5f);
        GA[threadIdx.x] = gw * gh;
    }

    int a = n >> 12, gj = (n >> 6) & 63, gi = n & 63;
    int base = ((b * NANCH * 5 + a * 5) * NGRID + gj) * NGRID + gi;
    float xs = sigm(out[base]);
    float ys = sigm(out[base + NGRID * NGRID]);
    float ws = sigm(out[base + 2 * NGRID * NGRID]);
    float hs = sigm(out[base + 3 * NGRID * NGRID]);
    float cf = sigm(out[base + 4 * NGRID * NGRID]);

    float bx = (xs + (float)gi) * (1.0f / NGRID);
    float by = (ys + (float)gj) * (1.0f / NGRID);
    float px1 = bx - ws * 0.5f, px2 = bx + ws * 0.5f;
    float py1 = by - hs * 0.5f, py2 = by + hs * 0.5f;
    float pa = ws * hs;

    Pxy[idx] = make_float4(px1, py1, px2, py2);
    Pac[idx] = make_float2(pa, cf);
    Bxy[threadIdx.x] = make_float4(px1, py1, px2, py2);
    Bpa[threadIdx.x] = pa;
    __syncthreads();                              // G4/GA + Bxy/Bpa ready

    // --- pd-side: this cell vs all 60 GTs (first-t tie-break)
    float best = -1e30f, biou = 0.0f;
    for (int t = 0; t < NT; ++t) {
        float4 g = G4[t];
        float iou, gou;
        gou_pair(px1, py1, px2, py2, pa, g.x, g.y, g.z, g.w, GA[t], iou, gou);
        if (gou > best) { best = gou; biou = iou; }
    }
    pd_gou[idx] = best;
    pd_iou[idx] = biou;

    // --- gt-side: lane = GT t; wave scans its 64 cells via LDS broadcast.
    {
        int t = (lane < NT) ? lane : 0;
        float4 g = G4[t];
        float ga = GA[t];
        int cbase = wave * 64;
        int nbase = s * 256 + cbase;
        unsigned long long bestp = 0ull;          // any real packed value >= 1<<32
#pragma unroll 4
        for (int i = 0; i < 64; ++i) {
            float4 p = Bxy[cbase + i];            // wave-uniform address: broadcast
            float cpa = Bpa[cbase + i];
            float iou, gou;
            gou_pair(p.x, p.y, p.z, p.w, cpa, g.x, g.y, g.z, g.w, ga, iou, gou);
            unsigned long long pk = ((unsigned long long)ford(gou) << 32)
                                  | (0xFFFFFFFFu - (unsigned int)(nbase + i));
            if (pk > bestp) bestp = pk;           // ascending n + strict > = first-index
        }
        if (lane < NT) atomicMax(&gtbest[b * NT + lane], bestp);
    }

    // --- fused heatmap MSE + pg
    float4 ha = io4[idx], hb = hm4[idx];
    float d0 = ha.x - hb.x, d1 = ha.y - hb.y, d2 = ha.z - hb.z, d3 = ha.w - hb.w;
    float hsum = d0 * d0 + d1 * d1 + d2 * d2 + d3 * d3;

    float v = waveSum(cf * cf);
    float h = waveSum(hsum);
    if (lane == 0) { red[wave] = v; red2[wave] = h; }
    __syncthreads();
    if (threadIdx.x == 0) {
        atomicAdd(&acc[A_PG], (double)(red[0] + red[1] + red[2] + red[3]));
        atomicAdd(&acc[A_HM], (double)(red2[0] + red2[1] + red2[2] + red2[3]));
    }
}

// ---------------------------------------------------------------------------
// Kernel D: per-batch. Prologue: unpack 60 gt winners (mask bits in LDS,
// iou recompute from stored boxes — same fast-rcp math as kB, so values
// match the winning pair's evaluation). Main loop: mask2/ignore/dice sums.
// ---------------------------------------------------------------------------
__global__ __launch_bounds__(256)
void kD_batch(const float4* __restrict__ Pxy, const float2* __restrict__ Pac,
              const float* __restrict__ pd_gou, const float* __restrict__ pd_iou,
              const unsigned int* __restrict__ obj_bits,
              const unsigned long long* __restrict__ gtbest,
              const float* __restrict__ labels, double* __restrict__ acc) {
    int b = blockIdx.x;
    __shared__ unsigned int mbits[NPB / 32];   // 384 words
    for (int w = threadIdx.x; w < NPB / 32; w += 256) mbits[w] = 0u;
    __syncthreads();

    float sgou = 0.f, siou = 0.f;
    if (threadIdx.x < NT) {
        int t = threadIdx.x;
        unsigned long long pk = gtbest[b * NT + t];
        float gou = ford_inv((unsigned int)(pk >> 32));
        int n = (int)(0xFFFFFFFFu - (unsigned int)(pk & 0xFFFFFFFFu));
        atomicOr(&mbits[n >> 5], 1u << (n & 31));
        int idx = b * NPB + n;
        float4 pbx = Pxy[idx];
        float pa = Pac[idx].x;
        const float* lp = labels + (b * NT + t) * 5;
        float gx = lp[1], gy = lp[2], gw = lp[3], gh = lp[4];
        float iou, gdummy;
        gou_pair(pbx.x, pbx.y, pbx.z, pbx.w, pa,
                 gx - gw * 0.5f, gy - gh * 0.5f, gx + gw * 0.5f, gy + gh * 0.5f,
                 gw * gh, iou, gdummy);
        sgou = 1.f - gou;
        siou = 1.f - iou;
    }
    if ((threadIdx.x >> 6) == 0) {             // wave 0 only (lanes 60-63 hold 0)
        float a1 = waveSum(sgou);
        float a2 = waveSum(siou);
        if (threadIdx.x == 0) {
            atomicAdd(&acc[A_GTGOU], (double)a1);
            atomicAdd(&acc[A_GTIOU], (double)a2);
        }
    }
    __syncthreads();

    float c2 = 0.f, sg = 0.f, si = 0.f, sin_ = 0.f, spa = 0.f, sga = 0.f;
    for (int n = threadIdx.x; n < NPB; n += 256) {
        int idx = b * NPB + n;
        float pio = pd_iou[idx];
        float pgo = pd_gou[idx];
        float cf = Pac[idx].y;
        bool mk = (pio >= 0.5f);
        bool m_ = (mbits[n >> 5] >> (n & 31)) & 1u;
        bool ob = (obj_bits[idx >> 5] >> (idx & 31)) & 1u;
        float m2 = (mk || m_) ? 1.f : 0.f;
        float ign = (!mk || m_) ? 1.f : 0.f;
        float tc = (ob || m_) ? 1.f : 0.f;
        c2 += m2;
        sg += (1.f - pgo) * m2;
        si += (1.f - pio) * m2;
        sin_ += cf * tc * ign;
        spa += cf * cf * ign;
        sga += tc * ign;
    }
    float vals[6] = { c2, sg, si, sin_, spa, sga };
    __shared__ float red[4];
    int wave = threadIdx.x >> 6, lane = threadIdx.x & 63;
#pragma unroll
    for (int k = 0; k < 6; ++k) {
        float v = waveSum(vals[k]);
        if (lane == 0) red[wave] = v;
        __syncthreads();
        if (threadIdx.x == 0) vals[k] = red[0] + red[1] + red[2] + red[3];
        __syncthreads();
    }
    if (threadIdx.x == 0) {
        atomicAdd(&acc[A_GOU2], (double)(vals[1] / vals[0]));
        atomicAdd(&acc[A_IOU2], (double)(vals[2] / vals[0]));
        float confb = 1.0f - (2.0f * vals[3] + 1.0f) / (vals[4] + vals[5] + 1.0f);
        atomicAdd(&acc[A_CONFB], (double)confb);
    }
}

// ---------------------------------------------------------------------------
// Kernel F: finalize the 7 outputs.
// ---------------------------------------------------------------------------
__global__ void kF_final(const double* __restrict__ acc, float* __restrict__ outp) {
    if (threadIdx.x == 0 && blockIdx.x == 0) {
        double cnt = acc[A_GG];
        double lxy = acc[A_XY] / cnt;
        double lwh = acc[A_WH] / cnt;
        double lgou = acc[A_GTGOU] / (double)NLBL + acc[A_GOU2] / (double)NBATCH;
        double liou = acc[A_GTIOU] / (double)NLBL + acc[A_IOU2] / (double)NBATCH;
        double dice = (2.0 * acc[A_IG] + 1.0) / (acc[A_PG] + acc[A_GG] + 1.0);
        if (dice != dice) dice = 1.0;
        double lconf = 1.0 - dice + acc[A_CONFB] / (double)NBATCH;
        double total = lxy + lwh + lconf + lgou;
        double hmv = acc[A_HM] / (double)(4 * NCELL);
        outp[0] = (float)lxy;
        outp[1] = (float)lwh;
        outp[2] = (float)lconf;
        outp[3] = (float)liou;
        outp[4] = (float)lgou;
        outp[5] = (float)total;
        outp[6] = (float)hmv;
    }
}

// ---------------------------------------------------------------------------
extern "C" void kernel_launch(void* const* d_in, const int* in_sizes, int n_in,
                              void* d_out, int out_size, void* d_ws, size_t ws_size,
                              hipStream_t stream) {
    const float* out_p    = (const float*)d_in[0];
    const float* labels   = (const float*)d_in[1];
    const float* int_out  = (const float*)d_in[2];
    const float* heatmaps = (const float*)d_in[3];
    float* o = (float*)d_out;

    char* ws = (char*)d_ws;
    const size_t BITS = NCELL / 8;                                  // 24576 B
    unsigned int* obj_bits = (unsigned int*)(ws);
    double* acc            = (double*)(ws + BITS);                  // 16 doubles (128 B)
    unsigned long long* gtbest =
        (unsigned long long*)(ws + BITS + 16 * sizeof(double));     // 960 u64 (7680 B)
    size_t hdr = BITS + 16 * sizeof(double) + (size_t)NLBL * 8;     // 32384, 16B-aligned
    float4* Pxy    = (float4*)(ws + hdr);
    float*  pd_gou = (float*)(ws + hdr + (size_t)NCELL * 16);
    float*  pd_iou = (float*)(ws + hdr + (size_t)NCELL * 20);
    float2* Pac    = (float2*)(ws + hdr + (size_t)NCELL * 24);

    // no memset: kA zeroes obj_bits/gtbest/acc; kB fully overwrites the rest.
    hipLaunchKernelGGL(kA_build_target, dim3(1), dim3(1024), 0, stream,
                       labels, out_p, obj_bits, gtbest, acc);
    hipLaunchKernelGGL(kB_main, dim3(NCELL / 256), dim3(256), 0, stream, out_p, labels,
                       (const float4*)int_out, (const float4*)heatmaps,
                       Pxy, Pac, pd_gou, pd_iou, gtbest, acc);
    hipLaunchKernelGGL(kD_batch, dim3(NBATCH), dim3(256), 0, stream, Pxy, Pac, pd_gou, pd_iou,
                       obj_bits, gtbest, labels, acc);
    hipLaunchKernelGGL(kF_final, dim3(1), dim3(64), 0, stream, acc, o);
}